// Round 1
// baseline (47.868 us; speedup 1.0000x reference)
//
#include <hip/hip_runtime.h>

// CrossNetwork: xl_{i+1} = x0 * dot(xl_i, W[i]) + b[i] + xl_i, CROSS=3.
// Row-independent; one 256-thread block per row, whole row in registers.
// Memory-bound: one read of x, one write of out (268 MB total).

constexpr int D_DIM  = 2048;
constexpr int NTHREADS = 256;
constexpr int CROSS  = 3;

__global__ __launch_bounds__(NTHREADS)
void cross_network_kernel(const float* __restrict__ x,
                          const float* __restrict__ W,
                          const float* __restrict__ bias,
                          float* __restrict__ out) {
    const int row  = blockIdx.x;
    const int t    = threadIdx.x;
    const int lane = t & 63;
    const int wave = t >> 6;

    // Each thread owns 8 floats of the row as two float4s:
    // elements [4t .. 4t+3] and [1024 + 4t .. 1024 + 4t+3].
    const float4* xr = reinterpret_cast<const float4*>(x + (size_t)row * D_DIM);
    const float4 x0a = xr[t];
    const float4 x0b = xr[t + NTHREADS];
    float4 xa = x0a;
    float4 xb = x0b;

    __shared__ float sred[CROSS][4];

#pragma unroll
    for (int i = 0; i < CROSS; ++i) {
        const float4* wr = reinterpret_cast<const float4*>(W + i * D_DIM);
        const float4 w0 = wr[t];
        const float4 w1 = wr[t + NTHREADS];

        // Per-thread partial dot of xl with W[i].
        float p = xa.x * w0.x + xa.y * w0.y + xa.z * w0.z + xa.w * w0.w
                + xb.x * w1.x + xb.y * w1.y + xb.z * w1.z + xb.w * w1.w;

        // Wave-64 reduction.
#pragma unroll
        for (int off = 32; off >= 1; off >>= 1)
            p += __shfl_down(p, off, 64);

        if (lane == 0) sred[i][wave] = p;
        __syncthreads();
        const float s = sred[i][0] + sred[i][1] + sred[i][2] + sred[i][3];

        const float4* br = reinterpret_cast<const float4*>(bias + i * D_DIM);
        const float4 b0 = br[t];
        const float4 b1 = br[t + NTHREADS];

        xa.x = fmaf(x0a.x, s, b0.x + xa.x);
        xa.y = fmaf(x0a.y, s, b0.y + xa.y);
        xa.z = fmaf(x0a.z, s, b0.z + xa.z);
        xa.w = fmaf(x0a.w, s, b0.w + xa.w);
        xb.x = fmaf(x0b.x, s, b1.x + xb.x);
        xb.y = fmaf(x0b.y, s, b1.y + xb.y);
        xb.z = fmaf(x0b.z, s, b1.z + xb.z);
        xb.w = fmaf(x0b.w, s, b1.w + xb.w);
        // No extra __syncthreads needed: next iteration writes sred[i+1][*],
        // a disjoint location, so readers of sred[i] can't race with it.
    }

    float4* outr = reinterpret_cast<float4*>(out + (size_t)row * D_DIM);
    outr[t]            = xa;
    outr[t + NTHREADS] = xb;
}

extern "C" void kernel_launch(void* const* d_in, const int* in_sizes, int n_in,
                              void* d_out, int out_size, void* d_ws, size_t ws_size,
                              hipStream_t stream) {
    const float* x    = (const float*)d_in[0];
    const float* W    = (const float*)d_in[1];
    const float* bias = (const float*)d_in[2];
    float* out = (float*)d_out;

    const int B = in_sizes[0] / D_DIM;  // 16384
    cross_network_kernel<<<B, NTHREADS, 0, stream>>>(x, W, bias, out);
}